// Round 1
// baseline (477.084 us; speedup 1.0000x reference)
//
#include <hip/hip_runtime.h>

#define N_NODES 50000
#define N_EDGES 600000
#define DIM 128
#define NGRAPH 128
#define NLAYER 4
#define BN_EPS 1e-5f
#define SCAN_BLK 1024

using short8  = __attribute__((ext_vector_type(8))) short;
using float4v = __attribute__((ext_vector_type(4))) float;

__device__ __forceinline__ float bf2f(unsigned short u) {
    union { unsigned int i; float f; } c; c.i = ((unsigned int)u) << 16; return c.f;
}
__device__ __forceinline__ unsigned short f2bf(float f) {
    union { float f; unsigned int i; } c; c.f = f;
    unsigned int x = c.i;
    return (unsigned short)((x + 0x7fffu + ((x >> 16) & 1u)) >> 16);
}

// ---------------- encode: h0 = value_W[fid%128] + vb + rwse@rwse_W + rb + deg_emb[deg] ----------------
__global__ void encode_kernel(const int* __restrict__ feat_id,
                              const float* __restrict__ rwse,
                              const int* __restrict__ indeg,
                              const float* __restrict__ value_W,
                              const float* __restrict__ value_b,
                              const float* __restrict__ rwse_W,
                              const float* __restrict__ rwse_b,
                              const float* __restrict__ deg_emb,
                              unsigned short* __restrict__ hout)
{
    int idx = blockIdx.x * blockDim.x + threadIdx.x;
    if (idx >= N_NODES * DIM) return;
    int n = idx >> 7, d = idx & 127;
    int fid = feat_id[n] & 127;
    float v = value_W[fid * DIM + d] + value_b[d] + rwse_b[d];
    const float* rr = rwse + n * 16;
    float acc = 0.f;
#pragma unroll
    for (int k = 0; k < 16; ++k) acc += rr[k] * rwse_W[k * DIM + d];
    v += acc;
    int dg = indeg[n]; dg = dg < 0 ? 0 : (dg > 1000 ? 1000 : dg);
    v += deg_emb[dg * DIM + d];
    hout[idx] = f2bf(v);
}

// ---------------- CSR build ----------------
__global__ void hist_kernel(const int* __restrict__ dst, int* __restrict__ cnt) {
    int e = blockIdx.x * blockDim.x + threadIdx.x;
    if (e < N_EDGES) atomicAdd(&cnt[dst[e]], 1);
}

__global__ void scanA_kernel(const int* __restrict__ cnt, int* __restrict__ rp, int* __restrict__ bsum) {
    __shared__ int sc[SCAN_BLK];
    int t = threadIdx.x, i = blockIdx.x * SCAN_BLK + t;
    int v = (i < N_NODES) ? cnt[i] : 0;
    sc[t] = v; __syncthreads();
    for (int off = 1; off < SCAN_BLK; off <<= 1) {
        int add = (t >= off) ? sc[t - off] : 0;
        __syncthreads();
        sc[t] += add;
        __syncthreads();
    }
    if (i < N_NODES) rp[i] = sc[t] - v;
    if (t == SCAN_BLK - 1) bsum[blockIdx.x] = sc[t];
}

__global__ void scanB_kernel(const int* __restrict__ bsum, int* __restrict__ bsx, int nb) {
    int lane = threadIdx.x;
    int v = (lane < nb) ? bsum[lane] : 0;
    int orig = v;
    for (int off = 1; off < 64; off <<= 1) {
        int y = __shfl_up(v, off, 64);
        if (lane >= off) v += y;
    }
    if (lane < nb) bsx[lane] = v - orig;
}

__global__ void scanC_kernel(int* __restrict__ rp, const int* __restrict__ bsx, int* __restrict__ cur) {
    int i = blockIdx.x * blockDim.x + threadIdx.x;
    if (i < N_NODES) { int v = rp[i] + bsx[i >> 10]; rp[i] = v; cur[i] = v; }
    else if (i == N_NODES) rp[i] = N_EDGES;
}

__global__ void scatter_kernel(const int* __restrict__ src, const int* __restrict__ dst,
                               int* __restrict__ cur, int* __restrict__ esrc) {
    int e = blockIdx.x * blockDim.x + threadIdx.x;
    if (e < N_EDGES) {
        int pos = atomicAdd(&cur[dst[e]], 1);
        esrc[pos] = src[e];
    }
}

// ---------------- weight transpose + bf16 convert (once per launch) ----------------
__global__ void wtrans_kernel(const float* __restrict__ W1, const float* __restrict__ W2,
                              unsigned short* __restrict__ w1t, unsigned short* __restrict__ w2t) {
    int idx = blockIdx.x * blockDim.x + threadIdx.x;
    if (idx >= 2 * NLAYER * DIM * DIM) return;
    int i = idx & (DIM * DIM - 1);
    int l = (idx >> 14) & 3;
    int is2 = idx >= NLAYER * DIM * DIM;
    int n = i >> 7, k = i & 127;
    const float* W = (is2 ? W2 : W1) + l * DIM * DIM;
    unsigned short v = f2bf(W[k * DIM + n]);
    (is2 ? w2t : w1t)[l * DIM * DIM + n * DIM + k] = v;
}

// ---------------- GIN aggregation: wave per node, agg = h[node] + sum_in h[src] ----------------
__global__ void __launch_bounds__(256) agg_kernel(const unsigned short* __restrict__ hin,
                                                  const int* __restrict__ rp,
                                                  const int* __restrict__ esrc,
                                                  unsigned short* __restrict__ aggout)
{
    int node = (blockIdx.x * blockDim.x + threadIdx.x) >> 6;
    if (node >= N_NODES) return;
    int lane = threadIdx.x & 63;
    int d0 = lane * 2;
    unsigned int q = *(const unsigned int*)(hin + node * DIM + d0);
    float a0 = bf2f((unsigned short)(q & 0xffff));
    float a1 = bf2f((unsigned short)(q >> 16));
    int e = rp[node], e1 = rp[node + 1];
    for (; e + 4 <= e1; e += 4) {
        int s0 = esrc[e], s1 = esrc[e + 1], s2 = esrc[e + 2], s3 = esrc[e + 3];
        unsigned int q0 = *(const unsigned int*)(hin + s0 * DIM + d0);
        unsigned int q1 = *(const unsigned int*)(hin + s1 * DIM + d0);
        unsigned int q2 = *(const unsigned int*)(hin + s2 * DIM + d0);
        unsigned int q3 = *(const unsigned int*)(hin + s3 * DIM + d0);
        a0 += bf2f((unsigned short)(q0 & 0xffff)) + bf2f((unsigned short)(q1 & 0xffff))
            + bf2f((unsigned short)(q2 & 0xffff)) + bf2f((unsigned short)(q3 & 0xffff));
        a1 += bf2f((unsigned short)(q0 >> 16)) + bf2f((unsigned short)(q1 >> 16))
            + bf2f((unsigned short)(q2 >> 16)) + bf2f((unsigned short)(q3 >> 16));
    }
    for (; e < e1; ++e) {
        int s = esrc[e];
        unsigned int qq = *(const unsigned int*)(hin + s * DIM + d0);
        a0 += bf2f((unsigned short)(qq & 0xffff));
        a1 += bf2f((unsigned short)(qq >> 16));
    }
    unsigned int packed = (unsigned int)f2bf(a0) | ((unsigned int)f2bf(a1) << 16);
    *(unsigned int*)(aggout + node * DIM + d0) = packed;
}

// ---------------- fused MLP: relu(agg@W1+b1)@W2+b2 -> BN -> ReLU ----------------
__global__ void __launch_bounds__(256, 2) mlp_kernel(
    const unsigned short* __restrict__ aggin,
    const unsigned short* __restrict__ w1t,
    const unsigned short* __restrict__ w2t,
    const float* __restrict__ b1, const float* __restrict__ b2,
    const float* __restrict__ gam, const float* __restrict__ bet,
    const float* __restrict__ mean, const float* __restrict__ var,
    unsigned short* __restrict__ hout, float* __restrict__ fout, int last)
{
    __shared__ unsigned short sA[DIM * DIM];
    __shared__ unsigned short sW[DIM * DIM];
    const int tid = threadIdx.x;
    const int wave = tid >> 6, lane = tid & 63;
    const int fr = lane & 15, fg = lane >> 4;
    const int rowbase = blockIdx.x * DIM;

    // stage W1^T (already [n][k] bf16) into sW, swizzled
    for (int i = tid * 8; i < DIM * DIM; i += 256 * 8) {
        short8 v = *(const short8*)(w1t + i);
        int n = i >> 7;
        int byte = i * 2; byte ^= (n & 7) << 4;
        *(short8*)((char*)sW + byte) = v;
    }
    // stage agg tile into sA, swizzled; zero-fill pad rows
    for (int i = tid * 8; i < DIM * DIM; i += 256 * 8) {
        int row = i >> 7;
        int node = rowbase + row;
        short8 v;
        if (node < N_NODES) v = *(const short8*)(aggin + (size_t)node * DIM + (i & 127));
        else { short z = 0; v = (short8){z,z,z,z,z,z,z,z}; }
        int byte = i * 2; byte ^= (row & 7) << 4;
        *(short8*)((char*)sA + byte) = v;
    }
    __syncthreads();

    // GEMM1: 4 waves, each 32 rows x 128 cols
    float4v acc[2][8];
#pragma unroll
    for (int m = 0; m < 2; ++m)
#pragma unroll
        for (int n = 0; n < 8; ++n) acc[m][n] = (float4v){0.f, 0.f, 0.f, 0.f};

#pragma unroll
    for (int ks = 0; ks < 4; ++ks) {
        int k0 = ks * 32 + fg * 8;
        short8 a0, a1;
        { int row = wave * 32 + fr;      int byte = row * 256 + k0 * 2; byte ^= (row & 7) << 4; a0 = *(const short8*)((char*)sA + byte); }
        { int row = wave * 32 + 16 + fr; int byte = row * 256 + k0 * 2; byte ^= (row & 7) << 4; a1 = *(const short8*)((char*)sA + byte); }
#pragma unroll
        for (int nb = 0; nb < 8; ++nb) {
            int col = nb * 16 + fr;
            int byte = col * 256 + k0 * 2; byte ^= (col & 7) << 4;
            short8 b = *(const short8*)((char*)sW + byte);
            acc[0][nb] = __builtin_amdgcn_mfma_f32_16x16x32_bf16(a0, b, acc[0][nb], 0, 0, 0);
            acc[1][nb] = __builtin_amdgcn_mfma_f32_16x16x32_bf16(a1, b, acc[1][nb], 0, 0, 0);
        }
    }
    __syncthreads();

    // bias + relu -> mid into sA (bf16); reload sW with W2^T
#pragma unroll
    for (int nb = 0; nb < 8; ++nb) {
        int col = nb * 16 + fr;
        float bias = b1[col];
#pragma unroll
        for (int m = 0; m < 2; ++m)
#pragma unroll
            for (int r = 0; r < 4; ++r) {
                int row = wave * 32 + m * 16 + fg * 4 + r;
                float v = acc[m][nb][r] + bias;
                v = fmaxf(v, 0.f);
                int byte = row * 256 + col * 2; byte ^= (row & 7) << 4;
                *(unsigned short*)((char*)sA + byte) = f2bf(v);
            }
    }
    for (int i = tid * 8; i < DIM * DIM; i += 256 * 8) {
        short8 v = *(const short8*)(w2t + i);
        int n = i >> 7;
        int byte = i * 2; byte ^= (n & 7) << 4;
        *(short8*)((char*)sW + byte) = v;
    }
    __syncthreads();

    // GEMM2
    float4v acc2[2][8];
#pragma unroll
    for (int m = 0; m < 2; ++m)
#pragma unroll
        for (int n = 0; n < 8; ++n) acc2[m][n] = (float4v){0.f, 0.f, 0.f, 0.f};

#pragma unroll
    for (int ks = 0; ks < 4; ++ks) {
        int k0 = ks * 32 + fg * 8;
        short8 a0, a1;
        { int row = wave * 32 + fr;      int byte = row * 256 + k0 * 2; byte ^= (row & 7) << 4; a0 = *(const short8*)((char*)sA + byte); }
        { int row = wave * 32 + 16 + fr; int byte = row * 256 + k0 * 2; byte ^= (row & 7) << 4; a1 = *(const short8*)((char*)sA + byte); }
#pragma unroll
        for (int nb = 0; nb < 8; ++nb) {
            int col = nb * 16 + fr;
            int byte = col * 256 + k0 * 2; byte ^= (col & 7) << 4;
            short8 b = *(const short8*)((char*)sW + byte);
            acc2[0][nb] = __builtin_amdgcn_mfma_f32_16x16x32_bf16(a0, b, acc2[0][nb], 0, 0, 0);
            acc2[1][nb] = __builtin_amdgcn_mfma_f32_16x16x32_bf16(a1, b, acc2[1][nb], 0, 0, 0);
        }
    }

    // epilogue: +b2, BN, ReLU, store
#pragma unroll
    for (int nb = 0; nb < 8; ++nb) {
        int col = nb * 16 + fr;
        float bias = b2[col];
        float iv = gam[col] * rsqrtf(var[col] + BN_EPS);
        float mn = mean[col], bt = bet[col];
#pragma unroll
        for (int m = 0; m < 2; ++m)
#pragma unroll
            for (int r = 0; r < 4; ++r) {
                int row = wave * 32 + m * 16 + fg * 4 + r;
                int node = rowbase + row;
                if (node < N_NODES) {
                    float v = acc2[m][nb][r] + bias;
                    v = (v - mn) * iv + bt;
                    v = fmaxf(v, 0.f);
                    if (last) fout[(size_t)node * DIM + col] = v;
                    else hout[(size_t)node * DIM + col] = f2bf(v);
                }
            }
    }
}

// ---------------- pooling: batch_idx sorted -> binary-search segment, block per graph ----------------
__global__ void pool_kernel(const float* __restrict__ h, const int* __restrict__ batch,
                            float* __restrict__ out)
{
    __shared__ float sums[256];
    __shared__ int sb[2];
    int g = blockIdx.x;
    if (threadIdx.x < 2) {
        int target = g + threadIdx.x;
        int lo = 0, hi = N_NODES;
        while (lo < hi) { int mid = (lo + hi) >> 1; if (batch[mid] < target) lo = mid + 1; else hi = mid; }
        sb[threadIdx.x] = lo;
    }
    __syncthreads();
    int lo = sb[0], hi = sb[1];
    int d = threadIdx.x & 127, half = threadIdx.x >> 7;
    float acc = 0.f;
    for (int n = lo + half; n < hi; n += 2) acc += h[(size_t)n * DIM + d];
    sums[threadIdx.x] = acc;
    __syncthreads();
    if (threadIdx.x < 128) {
        float s = sums[threadIdx.x] + sums[threadIdx.x + 128];
        float c = (float)(hi - lo);
        out[g * DIM + threadIdx.x] = s / fmaxf(c, 1.f);
    }
}

extern "C" void kernel_launch(void* const* d_in, const int* in_sizes, int n_in,
                              void* d_out, int out_size, void* d_ws, size_t ws_size,
                              hipStream_t stream)
{
    const int*   feat_id = (const int*)d_in[0];
    const int*   eidx    = (const int*)d_in[1];
    const int*   batch   = (const int*)d_in[2];
    const float* rwse    = (const float*)d_in[3];
    const int*   indeg   = (const int*)d_in[4];
    const float* value_W = (const float*)d_in[5];
    const float* value_b = (const float*)d_in[6];
    const float* rwse_W  = (const float*)d_in[7];
    const float* rwse_b  = (const float*)d_in[8];
    const float* deg_emb = (const float*)d_in[9];
    const float* W1      = (const float*)d_in[10];
    const float* b1      = (const float*)d_in[11];
    const float* W2      = (const float*)d_in[12];
    const float* b2      = (const float*)d_in[13];
    const float* gam     = (const float*)d_in[14];
    const float* bet     = (const float*)d_in[15];
    const float* mean    = (const float*)d_in[16];
    const float* var     = (const float*)d_in[17];

    const int* srcv = eidx;
    const int* dstv = eidx + N_EDGES;

    char* p = (char*)d_ws;
    auto alloc = [&](size_t bytes) { char* r = p; p += (bytes + 255) & ~(size_t)255; return r; };
    unsigned short* hA   = (unsigned short*)alloc((size_t)N_NODES * DIM * 2);
    unsigned short* agg  = (unsigned short*)alloc((size_t)N_NODES * DIM * 2);
    int* cnt  = (int*)alloc((size_t)N_NODES * 4);
    int* rp   = (int*)alloc((size_t)(N_NODES + 1) * 4);
    int* cur  = (int*)alloc((size_t)N_NODES * 4);
    int* bsum = (int*)alloc(64 * 4);
    int* bsx  = (int*)alloc(64 * 4);
    int* esrc = (int*)alloc((size_t)N_EDGES * 4);
    unsigned short* w1t = (unsigned short*)alloc((size_t)NLAYER * DIM * DIM * 2);
    unsigned short* w2t = (unsigned short*)alloc((size_t)NLAYER * DIM * DIM * 2);

    float* out = (float*)d_out;
    float* hf  = out + NGRAPH * DIM;   // h output region [N, D] f32

    hipMemsetAsync(cnt, 0, (size_t)N_NODES * 4, stream);
    encode_kernel<<<(N_NODES * DIM + 255) / 256, 256, 0, stream>>>(
        feat_id, rwse, indeg, value_W, value_b, rwse_W, rwse_b, deg_emb, hA);
    hist_kernel<<<(N_EDGES + 255) / 256, 256, 0, stream>>>(dstv, cnt);
    int nsb = (N_NODES + SCAN_BLK - 1) / SCAN_BLK;
    scanA_kernel<<<nsb, SCAN_BLK, 0, stream>>>(cnt, rp, bsum);
    scanB_kernel<<<1, 64, 0, stream>>>(bsum, bsx, nsb);
    scanC_kernel<<<(N_NODES + 256) / 256, 256, 0, stream>>>(rp, bsx, cur);
    scatter_kernel<<<(N_EDGES + 255) / 256, 256, 0, stream>>>(srcv, dstv, cur, esrc);
    wtrans_kernel<<<(2 * NLAYER * DIM * DIM + 255) / 256, 256, 0, stream>>>(W1, W2, w1t, w2t);

    const int nrb = (N_NODES + DIM - 1) / DIM;
    for (int l = 0; l < NLAYER; ++l) {
        agg_kernel<<<(N_NODES * 64 + 255) / 256, 256, 0, stream>>>(hA, rp, esrc, agg);
        mlp_kernel<<<nrb, 256, 0, stream>>>(agg,
            w1t + l * DIM * DIM, w2t + l * DIM * DIM,
            b1 + l * DIM, b2 + l * DIM, gam + l * DIM, bet + l * DIM,
            mean + l * DIM, var + l * DIM,
            hA, hf, (l == NLAYER - 1) ? 1 : 0);
    }
    pool_kernel<<<NGRAPH, 256, 0, stream>>>(hf, batch, out);
}

// Round 3
// 437.877 us; speedup vs baseline: 1.0895x; 1.0895x over previous
//
#include <hip/hip_runtime.h>

#define N_NODES 50000
#define N_EDGES 600000
#define DIM 128
#define NGRAPH 128
#define NLAYER 4
#define BN_EPS 1e-5f
#define SCAN_BLK 1024

using short8  = __attribute__((ext_vector_type(8))) short;
using float4v = __attribute__((ext_vector_type(4))) float;

__device__ __forceinline__ float bf2f(unsigned short u) {
    union { unsigned int i; float f; } c; c.i = ((unsigned int)u) << 16; return c.f;
}
__device__ __forceinline__ unsigned short f2bf(float f) {
    union { float f; unsigned int i; } c; c.f = f;
    unsigned int x = c.i;
    return (unsigned short)((x + 0x7fffu + ((x >> 16) & 1u)) >> 16);
}

// ---------------- encode: h0 = value_W[fid%128] + vb + rwse@rwse_W + rb + deg_emb[deg] ----------------
__global__ void encode_kernel(const int* __restrict__ feat_id,
                              const float* __restrict__ rwse,
                              const int* __restrict__ indeg,
                              const float* __restrict__ value_W,
                              const float* __restrict__ value_b,
                              const float* __restrict__ rwse_W,
                              const float* __restrict__ rwse_b,
                              const float* __restrict__ deg_emb,
                              unsigned short* __restrict__ hout)
{
    int idx = blockIdx.x * blockDim.x + threadIdx.x;
    if (idx >= N_NODES * DIM) return;
    int n = idx >> 7, d = idx & 127;
    int fid = feat_id[n] & 127;
    float v = value_W[fid * DIM + d] + value_b[d] + rwse_b[d];
    const float* rr = rwse + n * 16;
    float acc = 0.f;
#pragma unroll
    for (int k = 0; k < 16; ++k) acc += rr[k] * rwse_W[k * DIM + d];
    v += acc;
    int dg = indeg[n]; dg = dg < 0 ? 0 : (dg > 1000 ? 1000 : dg);
    v += deg_emb[dg * DIM + d];
    hout[idx] = f2bf(v);
}

// ---------------- CSR build ----------------
__global__ void hist_kernel(const int* __restrict__ dst, int* __restrict__ cnt) {
    int e = blockIdx.x * blockDim.x + threadIdx.x;
    if (e < N_EDGES) atomicAdd(&cnt[dst[e]], 1);
}

__global__ void scanA_kernel(const int* __restrict__ cnt, int* __restrict__ rp, int* __restrict__ bsum) {
    __shared__ int sc[SCAN_BLK];
    int t = threadIdx.x, i = blockIdx.x * SCAN_BLK + t;
    int v = (i < N_NODES) ? cnt[i] : 0;
    sc[t] = v; __syncthreads();
    for (int off = 1; off < SCAN_BLK; off <<= 1) {
        int add = (t >= off) ? sc[t - off] : 0;
        __syncthreads();
        sc[t] += add;
        __syncthreads();
    }
    if (i < N_NODES) rp[i] = sc[t] - v;
    if (t == SCAN_BLK - 1) bsum[blockIdx.x] = sc[t];
}

__global__ void scanB_kernel(const int* __restrict__ bsum, int* __restrict__ bsx, int nb) {
    int lane = threadIdx.x;
    int v = (lane < nb) ? bsum[lane] : 0;
    int orig = v;
    for (int off = 1; off < 64; off <<= 1) {
        int y = __shfl_up(v, off, 64);
        if (lane >= off) v += y;
    }
    if (lane < nb) bsx[lane] = v - orig;
}

__global__ void scanC_kernel(int* __restrict__ rp, const int* __restrict__ bsx, int* __restrict__ cur) {
    int i = blockIdx.x * blockDim.x + threadIdx.x;
    if (i < N_NODES) { int v = rp[i] + bsx[i >> 10]; rp[i] = v; cur[i] = v; }
    else if (i == N_NODES) rp[i] = N_EDGES;
}

__global__ void scatter_kernel(const int* __restrict__ src, const int* __restrict__ dst,
                               int* __restrict__ cur, int* __restrict__ esrc) {
    int e = blockIdx.x * blockDim.x + threadIdx.x;
    if (e < N_EDGES) {
        int pos = atomicAdd(&cur[dst[e]], 1);
        esrc[pos] = src[e];
    }
}

// ---------------- weight transpose + bf16 convert (once per launch) ----------------
__global__ void wtrans_kernel(const float* __restrict__ W1, const float* __restrict__ W2,
                              unsigned short* __restrict__ w1t, unsigned short* __restrict__ w2t) {
    int idx = blockIdx.x * blockDim.x + threadIdx.x;
    if (idx >= 2 * NLAYER * DIM * DIM) return;
    int i = idx & (DIM * DIM - 1);
    int l = (idx >> 14) & 3;
    int is2 = idx >= NLAYER * DIM * DIM;
    int n = i >> 7, k = i & 127;
    const float* W = (is2 ? W2 : W1) + l * DIM * DIM;
    unsigned short v = f2bf(W[k * DIM + n]);
    (is2 ? w2t : w1t)[l * DIM * DIM + n * DIM + k] = v;
}

// ---------------- GIN aggregation: wave per node, 4 neighbor-groups x 16 lanes x 16B ----------------
__global__ void __launch_bounds__(256) agg_kernel(const unsigned short* __restrict__ hin,
                                                  const int* __restrict__ rp,
                                                  const int* __restrict__ esrc,
                                                  unsigned short* __restrict__ aggout)
{
    int node = (blockIdx.x * blockDim.x + threadIdx.x) >> 6;
    if (node >= N_NODES) return;
    int lane = threadIdx.x & 63;
    int grp = lane >> 4, q = lane & 15;

    float a[8];
    if (grp == 0) {
        uint4 s = *(const uint4*)(hin + (size_t)node * DIM + q * 8);
        a[0] = bf2f((unsigned short)(s.x & 0xffff)); a[1] = bf2f((unsigned short)(s.x >> 16));
        a[2] = bf2f((unsigned short)(s.y & 0xffff)); a[3] = bf2f((unsigned short)(s.y >> 16));
        a[4] = bf2f((unsigned short)(s.z & 0xffff)); a[5] = bf2f((unsigned short)(s.z >> 16));
        a[6] = bf2f((unsigned short)(s.w & 0xffff)); a[7] = bf2f((unsigned short)(s.w >> 16));
    } else {
#pragma unroll
        for (int i = 0; i < 8; ++i) a[i] = 0.f;
    }

    int e1 = rp[node + 1];
    for (int e = rp[node] + grp; e < e1; e += 4) {
        int s = esrc[e];
        uint4 v = *(const uint4*)(hin + (size_t)s * DIM + q * 8);
        a[0] += bf2f((unsigned short)(v.x & 0xffff)); a[1] += bf2f((unsigned short)(v.x >> 16));
        a[2] += bf2f((unsigned short)(v.y & 0xffff)); a[3] += bf2f((unsigned short)(v.y >> 16));
        a[4] += bf2f((unsigned short)(v.z & 0xffff)); a[5] += bf2f((unsigned short)(v.z >> 16));
        a[6] += bf2f((unsigned short)(v.w & 0xffff)); a[7] += bf2f((unsigned short)(v.w >> 16));
    }

    // reduce across the 4 neighbor groups (lanes q, q+16, q+32, q+48)
#pragma unroll
    for (int i = 0; i < 8; ++i) {
        a[i] += __shfl_xor(a[i], 16, 64);
        a[i] += __shfl_xor(a[i], 32, 64);
    }

    if (grp == 0) {
        uint4 o;
        o.x = (unsigned int)f2bf(a[0]) | ((unsigned int)f2bf(a[1]) << 16);
        o.y = (unsigned int)f2bf(a[2]) | ((unsigned int)f2bf(a[3]) << 16);
        o.z = (unsigned int)f2bf(a[4]) | ((unsigned int)f2bf(a[5]) << 16);
        o.w = (unsigned int)f2bf(a[6]) | ((unsigned int)f2bf(a[7]) << 16);
        *(uint4*)(aggout + (size_t)node * DIM + q * 8) = o;
    }
}

// ---------------- fused MLP: relu(agg@W1+b1)@W2+b2 -> BN -> ReLU ----------------
__global__ void __launch_bounds__(256, 2) mlp_kernel(
    const unsigned short* __restrict__ aggin,
    const unsigned short* __restrict__ w1t,
    const unsigned short* __restrict__ w2t,
    const float* __restrict__ b1, const float* __restrict__ b2,
    const float* __restrict__ gam, const float* __restrict__ bet,
    const float* __restrict__ mean, const float* __restrict__ var,
    unsigned short* __restrict__ hout, float* __restrict__ fout, int last)
{
    __shared__ unsigned short sA[DIM * DIM];
    __shared__ unsigned short sW[DIM * DIM];
    const int tid = threadIdx.x;
    const int wave = tid >> 6, lane = tid & 63;
    const int fr = lane & 15, fg = lane >> 4;
    const int rowbase = blockIdx.x * DIM;

    for (int i = tid * 8; i < DIM * DIM; i += 256 * 8) {
        short8 v = *(const short8*)(w1t + i);
        int n = i >> 7;
        int byte = i * 2; byte ^= (n & 7) << 4;
        *(short8*)((char*)sW + byte) = v;
    }
    for (int i = tid * 8; i < DIM * DIM; i += 256 * 8) {
        int row = i >> 7;
        int node = rowbase + row;
        short8 v;
        if (node < N_NODES) v = *(const short8*)(aggin + (size_t)node * DIM + (i & 127));
        else { short z = 0; v = (short8){z,z,z,z,z,z,z,z}; }
        int byte = i * 2; byte ^= (row & 7) << 4;
        *(short8*)((char*)sA + byte) = v;
    }
    __syncthreads();

    float4v acc[2][8];
#pragma unroll
    for (int m = 0; m < 2; ++m)
#pragma unroll
        for (int n = 0; n < 8; ++n) acc[m][n] = (float4v){0.f, 0.f, 0.f, 0.f};

#pragma unroll
    for (int ks = 0; ks < 4; ++ks) {
        int k0 = ks * 32 + fg * 8;
        short8 a0, a1;
        { int row = wave * 32 + fr;      int byte = row * 256 + k0 * 2; byte ^= (row & 7) << 4; a0 = *(const short8*)((char*)sA + byte); }
        { int row = wave * 32 + 16 + fr; int byte = row * 256 + k0 * 2; byte ^= (row & 7) << 4; a1 = *(const short8*)((char*)sA + byte); }
#pragma unroll
        for (int nb = 0; nb < 8; ++nb) {
            int col = nb * 16 + fr;
            int byte = col * 256 + k0 * 2; byte ^= (col & 7) << 4;
            short8 b = *(const short8*)((char*)sW + byte);
            acc[0][nb] = __builtin_amdgcn_mfma_f32_16x16x32_bf16(a0, b, acc[0][nb], 0, 0, 0);
            acc[1][nb] = __builtin_amdgcn_mfma_f32_16x16x32_bf16(a1, b, acc[1][nb], 0, 0, 0);
        }
    }
    __syncthreads();

#pragma unroll
    for (int nb = 0; nb < 8; ++nb) {
        int col = nb * 16 + fr;
        float bias = b1[col];
#pragma unroll
        for (int m = 0; m < 2; ++m)
#pragma unroll
            for (int r = 0; r < 4; ++r) {
                int row = wave * 32 + m * 16 + fg * 4 + r;
                float v = acc[m][nb][r] + bias;
                v = fmaxf(v, 0.f);
                int byte = row * 256 + col * 2; byte ^= (row & 7) << 4;
                *(unsigned short*)((char*)sA + byte) = f2bf(v);
            }
    }
    for (int i = tid * 8; i < DIM * DIM; i += 256 * 8) {
        short8 v = *(const short8*)(w2t + i);
        int n = i >> 7;
        int byte = i * 2; byte ^= (n & 7) << 4;
        *(short8*)((char*)sW + byte) = v;
    }
    __syncthreads();

    float4v acc2[2][8];
#pragma unroll
    for (int m = 0; m < 2; ++m)
#pragma unroll
        for (int n = 0; n < 8; ++n) acc2[m][n] = (float4v){0.f, 0.f, 0.f, 0.f};

#pragma unroll
    for (int ks = 0; ks < 4; ++ks) {
        int k0 = ks * 32 + fg * 8;
        short8 a0, a1;
        { int row = wave * 32 + fr;      int byte = row * 256 + k0 * 2; byte ^= (row & 7) << 4; a0 = *(const short8*)((char*)sA + byte); }
        { int row = wave * 32 + 16 + fr; int byte = row * 256 + k0 * 2; byte ^= (row & 7) << 4; a1 = *(const short8*)((char*)sA + byte); }
#pragma unroll
        for (int nb = 0; nb < 8; ++nb) {
            int col = nb * 16 + fr;
            int byte = col * 256 + k0 * 2; byte ^= (col & 7) << 4;
            short8 b = *(const short8*)((char*)sW + byte);
            acc2[0][nb] = __builtin_amdgcn_mfma_f32_16x16x32_bf16(a0, b, acc2[0][nb], 0, 0, 0);
            acc2[1][nb] = __builtin_amdgcn_mfma_f32_16x16x32_bf16(a1, b, acc2[1][nb], 0, 0, 0);
        }
    }

#pragma unroll
    for (int nb = 0; nb < 8; ++nb) {
        int col = nb * 16 + fr;
        float bias = b2[col];
        float iv = gam[col] * rsqrtf(var[col] + BN_EPS);
        float mn = mean[col], bt = bet[col];
#pragma unroll
        for (int m = 0; m < 2; ++m)
#pragma unroll
            for (int r = 0; r < 4; ++r) {
                int row = wave * 32 + m * 16 + fg * 4 + r;
                int node = rowbase + row;
                if (node < N_NODES) {
                    float v = acc2[m][nb][r] + bias;
                    v = (v - mn) * iv + bt;
                    v = fmaxf(v, 0.f);
                    if (last) fout[(size_t)node * DIM + col] = v;
                    else hout[(size_t)node * DIM + col] = f2bf(v);
                }
            }
    }
}

// ---------------- pooling: 8 blocks per graph, atomic partial sums, then divide ----------------
__global__ void __launch_bounds__(256) pool_partial_kernel(const float* __restrict__ h,
                                                           const int* __restrict__ batch,
                                                           float* __restrict__ out)
{
    __shared__ float sums[256];
    __shared__ int sb[2];
    int g = blockIdx.x >> 3, split = blockIdx.x & 7;
    if (threadIdx.x < 2) {
        int target = g + threadIdx.x;
        int lo = 0, hi = N_NODES;
        while (lo < hi) { int mid = (lo + hi) >> 1; if (batch[mid] < target) lo = mid + 1; else hi = mid; }
        sb[threadIdx.x] = lo;
    }
    __syncthreads();
    int lo = sb[0], hi = sb[1];
    int d = threadIdx.x & 127, half = threadIdx.x >> 7;
    float acc = 0.f;
    for (int n = lo + split * 2 + half; n < hi; n += 16) acc += h[(size_t)n * DIM + d];
    sums[threadIdx.x] = acc;
    __syncthreads();
    if (threadIdx.x < 128) {
        float s = sums[threadIdx.x] + sums[threadIdx.x + 128];
        atomicAdd(&out[g * DIM + threadIdx.x], s);
    }
}

__global__ void pool_div_kernel(const int* __restrict__ batch, float* __restrict__ out)
{
    __shared__ int sb[2];
    int g = blockIdx.x;
    if (threadIdx.x < 2) {
        int target = g + threadIdx.x;
        int lo = 0, hi = N_NODES;
        while (lo < hi) { int mid = (lo + hi) >> 1; if (batch[mid] < target) lo = mid + 1; else hi = mid; }
        sb[threadIdx.x] = lo;
    }
    __syncthreads();
    float c = (float)(sb[1] - sb[0]);
    out[g * DIM + threadIdx.x] /= fmaxf(c, 1.f);
}

extern "C" void kernel_launch(void* const* d_in, const int* in_sizes, int n_in,
                              void* d_out, int out_size, void* d_ws, size_t ws_size,
                              hipStream_t stream)
{
    const int*   feat_id = (const int*)d_in[0];
    const int*   eidx    = (const int*)d_in[1];
    const int*   batch   = (const int*)d_in[2];
    const float* rwse    = (const float*)d_in[3];
    const int*   indeg   = (const int*)d_in[4];
    const float* value_W = (const float*)d_in[5];
    const float* value_b = (const float*)d_in[6];
    const float* rwse_W  = (const float*)d_in[7];
    const float* rwse_b  = (const float*)d_in[8];
    const float* deg_emb = (const float*)d_in[9];
    const float* W1      = (const float*)d_in[10];
    const float* b1      = (const float*)d_in[11];
    const float* W2      = (const float*)d_in[12];
    const float* b2      = (const float*)d_in[13];
    const float* gam     = (const float*)d_in[14];
    const float* bet     = (const float*)d_in[15];
    const float* mean    = (const float*)d_in[16];
    const float* var     = (const float*)d_in[17];

    const int* srcv = eidx;
    const int* dstv = eidx + N_EDGES;

    char* p = (char*)d_ws;
    auto alloc = [&](size_t bytes) { char* r = p; p += (bytes + 255) & ~(size_t)255; return r; };
    unsigned short* hA   = (unsigned short*)alloc((size_t)N_NODES * DIM * 2);
    unsigned short* agg  = (unsigned short*)alloc((size_t)N_NODES * DIM * 2);
    int* cnt  = (int*)alloc((size_t)N_NODES * 4);
    int* rp   = (int*)alloc((size_t)(N_NODES + 1) * 4);
    int* cur  = (int*)alloc((size_t)N_NODES * 4);
    int* bsum = (int*)alloc(64 * 4);
    int* bsx  = (int*)alloc(64 * 4);
    int* esrc = (int*)alloc((size_t)N_EDGES * 4);
    unsigned short* w1t = (unsigned short*)alloc((size_t)NLAYER * DIM * DIM * 2);
    unsigned short* w2t = (unsigned short*)alloc((size_t)NLAYER * DIM * DIM * 2);

    float* out = (float*)d_out;
    float* hf  = out + NGRAPH * DIM;   // h output region [N, D] f32

    hipMemsetAsync(cnt, 0, (size_t)N_NODES * 4, stream);
    hipMemsetAsync(out, 0, (size_t)NGRAPH * DIM * 4, stream);
    encode_kernel<<<(N_NODES * DIM + 255) / 256, 256, 0, stream>>>(
        feat_id, rwse, indeg, value_W, value_b, rwse_W, rwse_b, deg_emb, hA);
    hist_kernel<<<(N_EDGES + 255) / 256, 256, 0, stream>>>(dstv, cnt);
    int nsb = (N_NODES + SCAN_BLK - 1) / SCAN_BLK;
    scanA_kernel<<<nsb, SCAN_BLK, 0, stream>>>(cnt, rp, bsum);
    scanB_kernel<<<1, 64, 0, stream>>>(bsum, bsx, nsb);
    scanC_kernel<<<(N_NODES + 256) / 256, 256, 0, stream>>>(rp, bsx, cur);
    scatter_kernel<<<(N_EDGES + 255) / 256, 256, 0, stream>>>(srcv, dstv, cur, esrc);
    wtrans_kernel<<<(2 * NLAYER * DIM * DIM + 255) / 256, 256, 0, stream>>>(W1, W2, w1t, w2t);

    const int nrb = (N_NODES + DIM - 1) / DIM;
    for (int l = 0; l < NLAYER; ++l) {
        agg_kernel<<<(N_NODES * 64 + 255) / 256, 256, 0, stream>>>(hA, rp, esrc, agg);
        mlp_kernel<<<nrb, 256, 0, stream>>>(agg,
            w1t + l * DIM * DIM, w2t + l * DIM * DIM,
            b1 + l * DIM, b2 + l * DIM, gam + l * DIM, bet + l * DIM,
            mean + l * DIM, var + l * DIM,
            hA, hf, (l == NLAYER - 1) ? 1 : 0);
    }
    pool_partial_kernel<<<NGRAPH * 8, 256, 0, stream>>>(hf, batch, out);
    pool_div_kernel<<<NGRAPH, DIM, 0, stream>>>(batch, out);
}

// Round 4
// 432.032 us; speedup vs baseline: 1.1043x; 1.0135x over previous
//
#include <hip/hip_runtime.h>

#define N_NODES 50000
#define N_EDGES 600000
#define DIM 128
#define NGRAPH 128
#define NLAYER 4
#define BN_EPS 1e-5f
#define SCAN_BLK 1024
#define MROWS 64

#define EN_BLOCKS 25000   // N*D/256
#define WT_BLOCKS 512     // 2*L*D*D/256
#define HB_BLOCKS 2344    // ceil(E/256)

using short8  = __attribute__((ext_vector_type(8))) short;
using float4v = __attribute__((ext_vector_type(4))) float;

__device__ __forceinline__ float bf2f(unsigned short u) {
    union { unsigned int i; float f; } c; c.i = ((unsigned int)u) << 16; return c.f;
}
__device__ __forceinline__ unsigned short f2bf(float f) {
    union { float f; unsigned int i; } c; c.f = f;
    unsigned int x = c.i;
    return (unsigned short)((x + 0x7fffu + ((x >> 16) & 1u)) >> 16);
}

// ---------------- fused pre-pass: encode | weight-transpose | degree-histogram ----------------
__global__ void fused_pre_kernel(const int* __restrict__ feat_id,
                                 const float* __restrict__ rwse,
                                 const int* __restrict__ indeg,
                                 const float* __restrict__ value_W,
                                 const float* __restrict__ value_b,
                                 const float* __restrict__ rwse_W,
                                 const float* __restrict__ rwse_b,
                                 const float* __restrict__ deg_emb,
                                 unsigned short* __restrict__ hout,
                                 const float* __restrict__ W1,
                                 const float* __restrict__ W2,
                                 unsigned short* __restrict__ w1t,
                                 unsigned short* __restrict__ w2t,
                                 const int* __restrict__ dst,
                                 int* __restrict__ cnt)
{
    int b = blockIdx.x;
    if (b < EN_BLOCKS) {
        // encode: h0 = value_W[fid%128] + vb + rwse@rwse_W + rb + deg_emb[deg]
        int idx = b * 256 + threadIdx.x;            // exactly covers N*D
        int n = idx >> 7, d = idx & 127;
        int fid = feat_id[n] & 127;
        float v = value_W[fid * DIM + d] + value_b[d] + rwse_b[d];
        const float* rr = rwse + n * 16;
        float acc = 0.f;
#pragma unroll
        for (int k = 0; k < 16; ++k) acc += rr[k] * rwse_W[k * DIM + d];
        v += acc;
        int dg = indeg[n]; dg = dg < 0 ? 0 : (dg > 1000 ? 1000 : dg);
        v += deg_emb[dg * DIM + d];
        hout[idx] = f2bf(v);
    } else if (b < EN_BLOCKS + WT_BLOCKS) {
        // weight transpose + bf16 convert: w{1,2}t[l][n][k] = W{1,2}[l][k][n]
        int idx = (b - EN_BLOCKS) * 256 + threadIdx.x;   // exactly covers 2*L*D*D
        int i = idx & (DIM * DIM - 1);
        int l = (idx >> 14) & 3;
        int is2 = idx >= NLAYER * DIM * DIM;
        int n = i >> 7, k = i & 127;
        const float* W = (is2 ? W2 : W1) + l * DIM * DIM;
        unsigned short v = f2bf(W[k * DIM + n]);
        (is2 ? w2t : w1t)[l * DIM * DIM + n * DIM + k] = v;
    } else {
        int e = (b - EN_BLOCKS - WT_BLOCKS) * 256 + threadIdx.x;
        if (e < N_EDGES) atomicAdd(&cnt[dst[e]], 1);
    }
}

// ---------------- CSR build ----------------
__global__ void scanA_kernel(const int* __restrict__ cnt, int* __restrict__ rp, int* __restrict__ bsum) {
    __shared__ int sc[SCAN_BLK];
    int t = threadIdx.x, i = blockIdx.x * SCAN_BLK + t;
    int v = (i < N_NODES) ? cnt[i] : 0;
    sc[t] = v; __syncthreads();
    for (int off = 1; off < SCAN_BLK; off <<= 1) {
        int add = (t >= off) ? sc[t - off] : 0;
        __syncthreads();
        sc[t] += add;
        __syncthreads();
    }
    if (i < N_NODES) rp[i] = sc[t] - v;
    if (t == SCAN_BLK - 1) bsum[blockIdx.x] = sc[t];
}

// adds exclusive prefix of bsum (computed locally per block: nsb<=64 values) to rp
__global__ void scan_fixup_kernel(int* __restrict__ rp, const int* __restrict__ bsum,
                                  int* __restrict__ cur, int nsb) {
    __shared__ int sbx[64];
    int t = threadIdx.x;
    if (t < 64) {
        int v = (t < nsb) ? bsum[t] : 0;
        int orig = v;
        for (int off = 1; off < 64; off <<= 1) {
            int y = __shfl_up(v, off, 64);
            if (t >= off) v += y;
        }
        sbx[t] = v - orig;   // exclusive prefix
    }
    __syncthreads();
    int i = blockIdx.x * 256 + t;
    if (i < N_NODES) { int v = rp[i] + sbx[i >> 10]; rp[i] = v; cur[i] = v; }
    else if (i == N_NODES) rp[i] = N_EDGES;
}

__global__ void scatter_kernel(const int* __restrict__ src, const int* __restrict__ dst,
                               int* __restrict__ cur, int* __restrict__ esrc) {
    int e = blockIdx.x * blockDim.x + threadIdx.x;
    if (e < N_EDGES) {
        int pos = atomicAdd(&cur[dst[e]], 1);
        esrc[pos] = src[e];
    }
}

// ---------------- GIN aggregation: wave per node, 4 neighbor-groups x 16 lanes x 16B ----------------
__global__ void __launch_bounds__(256) agg_kernel(const unsigned short* __restrict__ hin,
                                                  const int* __restrict__ rp,
                                                  const int* __restrict__ esrc,
                                                  unsigned short* __restrict__ aggout)
{
    int node = (blockIdx.x * blockDim.x + threadIdx.x) >> 6;
    node = __builtin_amdgcn_readfirstlane(node);   // wave-uniform -> scalar addressing
    if (node >= N_NODES) return;
    int lane = threadIdx.x & 63;
    int grp = lane >> 4, q = lane & 15;

    float a[8];
    if (grp == 0) {
        uint4 s = *(const uint4*)(hin + (size_t)node * DIM + q * 8);
        a[0] = bf2f((unsigned short)(s.x & 0xffff)); a[1] = bf2f((unsigned short)(s.x >> 16));
        a[2] = bf2f((unsigned short)(s.y & 0xffff)); a[3] = bf2f((unsigned short)(s.y >> 16));
        a[4] = bf2f((unsigned short)(s.z & 0xffff)); a[5] = bf2f((unsigned short)(s.z >> 16));
        a[6] = bf2f((unsigned short)(s.w & 0xffff)); a[7] = bf2f((unsigned short)(s.w >> 16));
    } else {
#pragma unroll
        for (int i = 0; i < 8; ++i) a[i] = 0.f;
    }

    int e1 = rp[node + 1];
    int e = rp[node] + grp;
    int snext = (e < e1) ? esrc[e] : 0;
    while (e < e1) {
        int s = snext;
        int en = e + 4;
        snext = (en < e1) ? esrc[en] : 0;      // prefetch next index; independent of row load
        uint4 v = *(const uint4*)(hin + (size_t)s * DIM + q * 8);
        a[0] += bf2f((unsigned short)(v.x & 0xffff)); a[1] += bf2f((unsigned short)(v.x >> 16));
        a[2] += bf2f((unsigned short)(v.y & 0xffff)); a[3] += bf2f((unsigned short)(v.y >> 16));
        a[4] += bf2f((unsigned short)(v.z & 0xffff)); a[5] += bf2f((unsigned short)(v.z >> 16));
        a[6] += bf2f((unsigned short)(v.w & 0xffff)); a[7] += bf2f((unsigned short)(v.w >> 16));
        e = en;
    }

#pragma unroll
    for (int i = 0; i < 8; ++i) {
        a[i] += __shfl_xor(a[i], 16, 64);
        a[i] += __shfl_xor(a[i], 32, 64);
    }

    if (grp == 0) {
        uint4 o;
        o.x = (unsigned int)f2bf(a[0]) | ((unsigned int)f2bf(a[1]) << 16);
        o.y = (unsigned int)f2bf(a[2]) | ((unsigned int)f2bf(a[3]) << 16);
        o.z = (unsigned int)f2bf(a[4]) | ((unsigned int)f2bf(a[5]) << 16);
        o.w = (unsigned int)f2bf(a[6]) | ((unsigned int)f2bf(a[7]) << 16);
        *(uint4*)(aggout + (size_t)node * DIM + q * 8) = o;
    }
}

// ---------------- fused MLP: relu(agg@W1+b1)@W2+b2 -> BN -> ReLU  (64-row tile, 3 blk/CU) ----------------
__global__ void __launch_bounds__(256, 3) mlp_kernel(
    const unsigned short* __restrict__ aggin,
    const unsigned short* __restrict__ w1t,
    const unsigned short* __restrict__ w2t,
    const float* __restrict__ b1, const float* __restrict__ b2,
    const float* __restrict__ gam, const float* __restrict__ bet,
    const float* __restrict__ mean, const float* __restrict__ var,
    unsigned short* __restrict__ hout, float* __restrict__ fout, int last)
{
    __shared__ unsigned short sA[MROWS * DIM];   // 16 KB
    __shared__ unsigned short sW[DIM * DIM];     // 32 KB
    const int tid = threadIdx.x;
    const int wave = tid >> 6, lane = tid & 63;
    const int fr = lane & 15, fg = lane >> 4;
    const int rowbase = blockIdx.x * MROWS;

    for (int i = tid * 8; i < DIM * DIM; i += 256 * 8) {
        short8 v = *(const short8*)(w1t + i);
        int n = i >> 7;
        int byte = i * 2; byte ^= (n & 7) << 4;
        *(short8*)((char*)sW + byte) = v;
    }
    for (int i = tid * 8; i < MROWS * DIM; i += 256 * 8) {
        int row = i >> 7;
        int node = rowbase + row;
        short8 v;
        if (node < N_NODES) v = *(const short8*)(aggin + (size_t)node * DIM + (i & 127));
        else { short z = 0; v = (short8){z,z,z,z,z,z,z,z}; }
        int byte = i * 2; byte ^= (row & 7) << 4;
        *(short8*)((char*)sA + byte) = v;
    }
    __syncthreads();

    // GEMM1: each wave owns 16 rows x 128 cols
    float4v acc[8];
#pragma unroll
    for (int n = 0; n < 8; ++n) acc[n] = (float4v){0.f, 0.f, 0.f, 0.f};

#pragma unroll
    for (int ks = 0; ks < 4; ++ks) {
        int k0 = ks * 32 + fg * 8;
        short8 a0;
        { int row = wave * 16 + fr; int byte = row * 256 + k0 * 2; byte ^= (row & 7) << 4; a0 = *(const short8*)((char*)sA + byte); }
#pragma unroll
        for (int nb = 0; nb < 8; ++nb) {
            int col = nb * 16 + fr;
            int byte = col * 256 + k0 * 2; byte ^= (col & 7) << 4;
            short8 b = *(const short8*)((char*)sW + byte);
            acc[nb] = __builtin_amdgcn_mfma_f32_16x16x32_bf16(a0, b, acc[nb], 0, 0, 0);
        }
    }
    __syncthreads();

    // mid: bias + relu -> bf16 back into sA; reload sW with W2^T
#pragma unroll
    for (int nb = 0; nb < 8; ++nb) {
        int col = nb * 16 + fr;
        float bias = b1[col];
#pragma unroll
        for (int r = 0; r < 4; ++r) {
            int row = wave * 16 + fg * 4 + r;
            float v = acc[nb][r] + bias;
            v = fmaxf(v, 0.f);
            int byte = row * 256 + col * 2; byte ^= (row & 7) << 4;
            *(unsigned short*)((char*)sA + byte) = f2bf(v);
        }
    }
    for (int i = tid * 8; i < DIM * DIM; i += 256 * 8) {
        short8 v = *(const short8*)(w2t + i);
        int n = i >> 7;
        int byte = i * 2; byte ^= (n & 7) << 4;
        *(short8*)((char*)sW + byte) = v;
    }
    __syncthreads();

    // GEMM2
    float4v acc2[8];
#pragma unroll
    for (int n = 0; n < 8; ++n) acc2[n] = (float4v){0.f, 0.f, 0.f, 0.f};

#pragma unroll
    for (int ks = 0; ks < 4; ++ks) {
        int k0 = ks * 32 + fg * 8;
        short8 a0;
        { int row = wave * 16 + fr; int byte = row * 256 + k0 * 2; byte ^= (row & 7) << 4; a0 = *(const short8*)((char*)sA + byte); }
#pragma unroll
        for (int nb = 0; nb < 8; ++nb) {
            int col = nb * 16 + fr;
            int byte = col * 256 + k0 * 2; byte ^= (col & 7) << 4;
            short8 b = *(const short8*)((char*)sW + byte);
            acc2[nb] = __builtin_amdgcn_mfma_f32_16x16x32_bf16(a0, b, acc2[nb], 0, 0, 0);
        }
    }

    // epilogue: +b2, BN, ReLU, store
#pragma unroll
    for (int nb = 0; nb < 8; ++nb) {
        int col = nb * 16 + fr;
        float bias = b2[col];
        float iv = gam[col] * rsqrtf(var[col] + BN_EPS);
        float mn = mean[col], bt = bet[col];
#pragma unroll
        for (int r = 0; r < 4; ++r) {
            int row = wave * 16 + fg * 4 + r;
            int node = rowbase + row;
            if (node < N_NODES) {
                float v = acc2[nb][r] + bias;
                v = (v - mn) * iv + bt;
                v = fmaxf(v, 0.f);
                if (last) fout[(size_t)node * DIM + col] = v;
                else hout[(size_t)node * DIM + col] = f2bf(v);
            }
        }
    }
}

// ---------------- pooling: 8 blocks/graph non-atomic partials, then combine+divide ----------------
__global__ void __launch_bounds__(256) pool_partial_kernel(const float* __restrict__ h,
                                                           const int* __restrict__ batch,
                                                           float* __restrict__ partial)
{
    __shared__ float sums[256];
    __shared__ int sb[2];
    int g = blockIdx.x >> 3, split = blockIdx.x & 7;
    if (threadIdx.x < 2) {
        int target = g + threadIdx.x;
        int lo = 0, hi = N_NODES;
        while (lo < hi) { int mid = (lo + hi) >> 1; if (batch[mid] < target) lo = mid + 1; else hi = mid; }
        sb[threadIdx.x] = lo;
    }
    __syncthreads();
    int lo = sb[0], hi = sb[1];
    int d = threadIdx.x & 127, half = threadIdx.x >> 7;
    float acc = 0.f;
    for (int n = lo + split * 2 + half; n < hi; n += 16) acc += h[(size_t)n * DIM + d];
    sums[threadIdx.x] = acc;
    __syncthreads();
    if (threadIdx.x < 128)
        partial[blockIdx.x * DIM + threadIdx.x] = sums[threadIdx.x] + sums[threadIdx.x + 128];
}

__global__ void pool_comb_kernel(const float* __restrict__ partial,
                                 const int* __restrict__ batch,
                                 float* __restrict__ out)
{
    __shared__ int sb[2];
    int g = blockIdx.x, t = threadIdx.x;
    if (t < 2) {
        int target = g + t;
        int lo = 0, hi = N_NODES;
        while (lo < hi) { int mid = (lo + hi) >> 1; if (batch[mid] < target) lo = mid + 1; else hi = mid; }
        sb[t] = lo;
    }
    __syncthreads();
    float s = 0.f;
#pragma unroll
    for (int sp = 0; sp < 8; ++sp) s += partial[(g * 8 + sp) * DIM + t];
    float c = (float)(sb[1] - sb[0]);
    out[g * DIM + t] = s / fmaxf(c, 1.f);
}

extern "C" void kernel_launch(void* const* d_in, const int* in_sizes, int n_in,
                              void* d_out, int out_size, void* d_ws, size_t ws_size,
                              hipStream_t stream)
{
    const int*   feat_id = (const int*)d_in[0];
    const int*   eidx    = (const int*)d_in[1];
    const int*   batch   = (const int*)d_in[2];
    const float* rwse    = (const float*)d_in[3];
    const int*   indeg   = (const int*)d_in[4];
    const float* value_W = (const float*)d_in[5];
    const float* value_b = (const float*)d_in[6];
    const float* rwse_W  = (const float*)d_in[7];
    const float* rwse_b  = (const float*)d_in[8];
    const float* deg_emb = (const float*)d_in[9];
    const float* W1      = (const float*)d_in[10];
    const float* b1      = (const float*)d_in[11];
    const float* W2      = (const float*)d_in[12];
    const float* b2      = (const float*)d_in[13];
    const float* gam     = (const float*)d_in[14];
    const float* bet     = (const float*)d_in[15];
    const float* mean    = (const float*)d_in[16];
    const float* var     = (const float*)d_in[17];

    const int* srcv = eidx;
    const int* dstv = eidx + N_EDGES;

    char* p = (char*)d_ws;
    auto alloc = [&](size_t bytes) { char* r = p; p += (bytes + 255) & ~(size_t)255; return r; };
    unsigned short* hA   = (unsigned short*)alloc((size_t)N_NODES * DIM * 2);
    unsigned short* agg  = (unsigned short*)alloc((size_t)N_NODES * DIM * 2);
    int* cnt  = (int*)alloc((size_t)N_NODES * 4);
    int* rp   = (int*)alloc((size_t)(N_NODES + 1) * 4);
    int* cur  = (int*)alloc((size_t)N_NODES * 4);
    int* bsum = (int*)alloc(64 * 4);
    int* esrc = (int*)alloc((size_t)N_EDGES * 4);
    unsigned short* w1t = (unsigned short*)alloc((size_t)NLAYER * DIM * DIM * 2);
    unsigned short* w2t = (unsigned short*)alloc((size_t)NLAYER * DIM * DIM * 2);
    float* partial = (float*)alloc((size_t)NGRAPH * 8 * DIM * 4);

    float* out = (float*)d_out;
    float* hf  = out + NGRAPH * DIM;   // h output region [N, D] f32

    hipMemsetAsync(cnt, 0, (size_t)N_NODES * 4, stream);
    fused_pre_kernel<<<EN_BLOCKS + WT_BLOCKS + HB_BLOCKS, 256, 0, stream>>>(
        feat_id, rwse, indeg, value_W, value_b, rwse_W, rwse_b, deg_emb, hA,
        W1, W2, w1t, w2t, dstv, cnt);
    int nsb = (N_NODES + SCAN_BLK - 1) / SCAN_BLK;   // 49
    scanA_kernel<<<nsb, SCAN_BLK, 0, stream>>>(cnt, rp, bsum);
    scan_fixup_kernel<<<(N_NODES + 1 + 255) / 256, 256, 0, stream>>>(rp, bsum, cur, nsb);
    scatter_kernel<<<(N_EDGES + 255) / 256, 256, 0, stream>>>(srcv, dstv, cur, esrc);

    const int nrb = (N_NODES + MROWS - 1) / MROWS;
    for (int l = 0; l < NLAYER; ++l) {
        agg_kernel<<<(N_NODES * 64 + 255) / 256, 256, 0, stream>>>(hA, rp, esrc, agg);
        mlp_kernel<<<nrb, 256, 0, stream>>>(agg,
            w1t + l * DIM * DIM, w2t + l * DIM * DIM,
            b1 + l * DIM, b2 + l * DIM, gam + l * DIM, bet + l * DIM,
            mean + l * DIM, var + l * DIM,
            hA, hf, (l == NLAYER - 1) ? 1 : 0);
    }
    pool_partial_kernel<<<NGRAPH * 8, 256, 0, stream>>>(hf, batch, partial);
    pool_comb_kernel<<<NGRAPH, DIM, 0, stream>>>(partial, batch, out);
}